// Round 14
// baseline (289.643 us; speedup 1.0000x reference)
//
#include <hip/hip_runtime.h>
#include <math.h>
#include <stdint.h>

// Problem constants
#define NN    50000
#define EPOS  400000
#define ROWS  800000
#define DIM   128
#define D2    256
#define H1C   256
#define H2C   128
#define MT    64            // edge rows per block
#define NTH   512           // 8 waves

typedef __bf16 bf16;
typedef __bf16 bf16x8 __attribute__((ext_vector_type(8)));
typedef __bf16 bf16x4 __attribute__((ext_vector_type(4)));
typedef float  f32x4  __attribute__((ext_vector_type(4)));

// ---- workspace element offsets (bf16 elements) ----
#define XB_N   (NN*DIM)             // 6,400,000: x as bf16 [node][128]
#define WAF_E  XB_N
#define WAF_N  (128*512)            // 65,536: wA fragment order (new) / w1f (old path)
#define W2F_E  (WAF_E + WAF_N)
#define W2F_N  (H2C*H1C)            // 32,768
#define Y_E    (W2F_E + W2F_N)
#define Y_N    (NN*512)             // 25,600,000: Y[node][512] = [ytop+b1 | ybot]
#define WS1_NEEDED ((size_t)(W2F_E + W2F_N) * 2)     // ~13.0 MB (old path)
#define WS2_NEEDED ((size_t)(Y_E + Y_N) * 2)         // ~64.2 MB (new path)

__device__ __forceinline__ void gll16(const void* g, void* l) {
    __builtin_amdgcn_global_load_lds(
        (const __attribute__((address_space(1))) void*)g,
        (__attribute__((address_space(3))) void*)l, 16, 0, 0);
}

// ===================== preconv2 (new path): x->bf16, wA frags, w2 frags, labels ==
// wA[k][n'] (k<128, n'<512): n'<256 -> w1[k][n'] (top half rows), else w1[128+k][n'-256].
// wAf flat = ((c*32 + t)*64 + l)*8 + j ; n' = t*16 + (l&15), k = c*32 + (l>>4)*8 + j (c<4)
// w2f flat = ((c*8  + t)*64 + l)*8 + j ; n = t*16+(l&15), k = c*32+(l>>4)*8+j (c<8,t<8)
__global__ void preconv2(const float* __restrict__ x, const float* __restrict__ w1,
                         const float* __restrict__ w2, bf16* __restrict__ ws,
                         float* __restrict__ out) {
    int gi = blockIdx.x * 256 + threadIdx.x;
    if (gi < ROWS) out[ROWS + gi] = (gi < EPOS) ? 1.f : 0.f;   // labels
    int i = gi;
    if (i < XB_N) { ws[i] = (bf16)x[i]; return; }
    i -= XB_N;
    if (i < WAF_N) {
        int j = i & 7, l = (i >> 3) & 63, ct = i >> 9;   // ct 0..127
        int c = ct >> 5, t = ct & 31;
        int np = t * 16 + (l & 15);
        int k  = c * 32 + (l >> 4) * 8 + j;
        float v = (np < 256) ? w1[k * H1C + np] : w1[(128 + k) * H1C + (np - 256)];
        ws[WAF_E + i] = (bf16)v;
        return;
    }
    i -= WAF_N;
    if (i < W2F_N) {
        int j = i & 7, l = (i >> 3) & 63, ct = i >> 9;   // ct 0..63
        int c = ct >> 3, t = ct & 7;
        int n = t * 16 + (l & 15);
        int k = c * 32 + (l >> 4) * 8 + j;
        ws[W2F_E + i] = (bf16)w2[k * H2C + n];
    }
}

// ===================== node GEMM: Y[node][512] = [x@w1_top + b1 | x@w1_bot] ======
__global__ __launch_bounds__(512, 4) void node_gemm(
    const bf16* __restrict__ xb, const bf16* __restrict__ waf,
    const float* __restrict__ b1, bf16* __restrict__ Y)
{
    __shared__ char smem[16384];     // x tile [64 rows][256B], 3-bit XOR swizzle
    const int tid  = threadIdx.x;
    const int lane = tid & 63;
    const int w    = tid >> 6;       // 0..7
    const int wm   = w >> 2;         // 0..1 (32 rows)
    const int wn   = w & 3;          // 0..3 (128 cols)
    const int n0   = blockIdx.x * 64;
    const int l15  = lane & 15;
    const int l4   = lane >> 4;

    // stage x rows (256B each), 16 units of 1KB
    #pragma unroll
    for (int ii = 0; ii < 2; ++ii) {
        const int i = w * 2 + ii;
        uint32_t doff = (uint32_t)(i << 10) + (uint32_t)(lane << 4);
        uint32_t loff = doff ^ (((doff >> 8) & 7u) << 4);
        int row  = loff >> 8;
        int inb  = loff & 255;
        int node = n0 + row; if (node >= NN) node = NN - 1;
        gll16((const char*)xb + ((size_t)node << 8) + inb, smem + (i << 10));
    }
    __syncthreads();

    // GEMM (swapped): D[col'][node]; per lane node=..+l15, col'=wn*128+ni*16+l4*4+j
    f32x4 acc[2][8] = {};
    const bf16* bp = waf + (wn << 12) + (lane << 3);    // t = wn*8+ni
    uint32_t abase[2], asw[2];
    #pragma unroll
    for (int mi = 0; mi < 2; ++mi) {
        int row = (wm << 5) + (mi << 4) + l15;
        abase[mi] = (uint32_t)row << 8;
        asw[mi]   = (uint32_t)(row & 7) << 4;
    }
    #pragma unroll
    for (int c = 0; c < 4; ++c) {
        bf16x8 af[2];
        #pragma unroll
        for (int mi = 0; mi < 2; ++mi)
            af[mi] = *(const bf16x8*)(smem + ((abase[mi] + ((uint32_t)c << 6) + ((uint32_t)l4 << 4)) ^ asw[mi]));
        #pragma unroll
        for (int ni = 0; ni < 8; ++ni) {
            bf16x8 bfr = *(const bf16x8*)(bp + (c << 14) + (ni << 9));
            #pragma unroll
            for (int mi = 0; mi < 2; ++mi)
                acc[mi][ni] = __builtin_amdgcn_mfma_f32_16x16x32_bf16(
                    bfr, af[mi], acc[mi][ni], 0, 0, 0);
        }
    }

    // epilogue: +b1 for cols<256 (wn<2), cvt, store
    #pragma unroll
    for (int mi = 0; mi < 2; ++mi) {
        int node = n0 + (wm << 5) + (mi << 4) + l15;
        if (node >= NN) continue;
        #pragma unroll
        for (int ni = 0; ni < 8; ++ni) {
            int col = (wn << 7) + (ni << 4) + (l4 << 2);
            f32x4 a = acc[mi][ni];
            if (wn < 2) {
                f32x4 bv = *(const f32x4*)(b1 + col);
                a[0] += bv[0]; a[1] += bv[1]; a[2] += bv[2]; a[3] += bv[3];
            }
            bf16x4 ob;
            #pragma unroll
            for (int j = 0; j < 4; ++j) ob[j] = (bf16)a[j];
            *(bf16x4*)(Y + ((size_t)node << 9) + col) = ob;
        }
    }
}

// ===================== edge kernel: gather Y halves, add, LN1, GEMM2, LN2, out ===
#define SOFF  0        // 32KB: S = Y[src][0:256] rows (512B, swizzled); becomes h1
#define DOFF  32768    // 32KB: D = Y[dst][256:512]
#define BSCR  65536    // 2KB  LN scratch
#define BSCR2 67584    // 1KB  z scratch
#define BCF   68608    // 4KB: g1[256] be1[256] b2[128] g2[128] be2[128] w3[128]
#define BSMEM 72704

__global__ __launch_bounds__(NTH, 4) void lp_edge(
    const bf16* __restrict__ Y, const bf16* __restrict__ w2f,
    const int*  __restrict__ ei, const int* __restrict__ nei,
    const float* __restrict__ g1, const float* __restrict__ be1,
    const float* __restrict__ b2, const float* __restrict__ g2, const float* __restrict__ be2,
    const float* __restrict__ w3, const float* __restrict__ b3,
    float* __restrict__ out)
{
    extern __shared__ char smem[];
    const int tid  = threadIdx.x;
    const int lane = tid & 63;
    const int w    = tid >> 6;
    const int wm   = w >> 2;
    const int wn   = w & 3;
    const int gr0  = blockIdx.x * MT;
    const int l15  = lane & 15;
    const int l4   = lane >> 4;

    // ---- stage S (units 0..31) and D (units 32..63), 1KB each, swizzled ----
    #pragma unroll
    for (int ii = 0; ii < 8; ++ii) {
        const int i = w * 8 + ii;
        const int u = i & 31;
        const int half = i >> 5;                          // 0=S(src,top), 1=D(dst,bot)
        uint32_t doff = (uint32_t)(u << 10) + (uint32_t)(lane << 4);
        uint32_t loff = doff ^ (((doff >> 9) & 7u) << 4);
        int row = loff >> 9;
        int inb = loff & 511;
        int gr  = gr0 + row;
        int node = (half == 0) ? ((gr < EPOS) ? ei[gr]        : nei[gr - EPOS])
                               : ((gr < EPOS) ? ei[EPOS + gr] : nei[gr]);
        gll16((const char*)Y + ((size_t)node << 10) + (half << 9) + inb,
              smem + (half ? DOFF : SOFF) + (u << 10));
    }

    // ---- stage coeffs into LDS (1024 f32) ----
    for (int i = tid; i < 1024; i += NTH) {
        float v;
        if      (i < 256) v = g1[i];
        else if (i < 512) v = be1[i - 256];
        else if (i < 640) v = b2[i - 512];
        else if (i < 768) v = g2[i - 640];
        else if (i < 896) v = be2[i - 768];
        else              v = w3[i - 896];
        *(float*)(smem + BCF + i * 4) = v;
    }

    uint32_t abase[2], asw[2];
    #pragma unroll
    for (int mi = 0; mi < 2; ++mi) {
        int row = (wm << 5) + (mi << 4) + l15;
        abase[mi] = (uint32_t)row << 9;
        asw[mi]   = (uint32_t)(row & 7) << 4;
    }
    const uint32_t koff  = (uint32_t)l4 << 4;
    const uint32_t c1off = ((uint32_t)wn << 8) + ((uint32_t)l4 << 4);
    const uint32_t c2off = ((uint32_t)wn << 7) + ((uint32_t)l4 << 4);

    __syncthreads();

    // ---- LN1 stats: pv = S + D (pre-LN h1), in-register ----
    f32x4 pv[2][4];
    #pragma unroll
    for (int mi = 0; mi < 2; ++mi) {
        float s1 = 0.f, s2 = 0.f;
        int row = (wm << 5) + (mi << 4) + l15;
        uint32_t rsw = (uint32_t)(row & 7) << 4;
        #pragma unroll
        for (int ni = 0; ni < 4; ++ni) {
            uint32_t byte = (((uint32_t)row << 9) + ((uint32_t)wn << 7) + ((uint32_t)ni << 5) + ((uint32_t)l4 << 3)) ^ rsw;
            bf16x4 sv = *(const bf16x4*)(smem + SOFF + byte);
            bf16x4 dv = *(const bf16x4*)(smem + DOFF + byte);
            f32x4 v;
            #pragma unroll
            for (int j = 0; j < 4; ++j) {
                v[j] = (float)sv[j] + (float)dv[j];
                s1 += v[j]; s2 += v[j] * v[j];
            }
            pv[mi][ni] = v;
        }
        s1 += __shfl_xor(s1, 16); s1 += __shfl_xor(s1, 32);
        s2 += __shfl_xor(s2, 16); s2 += __shfl_xor(s2, 32);
        if (l4 == 0)
            *(float2*)(smem + BSCR + (row << 5) + (wn << 3)) = make_float2(s1, s2);
    }
    __syncthreads();

    // ---- LN1 apply + ReLU -> h1 (overwrites S) ----
    #pragma unroll
    for (int mi = 0; mi < 2; ++mi) {
        int row = (wm << 5) + (mi << 4) + l15;
        f32x4 p0 = *(const f32x4*)(smem + BSCR + (row << 5));
        f32x4 p1 = *(const f32x4*)(smem + BSCR + (row << 5) + 16);
        float s1 = p0[0] + p0[2] + p1[0] + p1[2];
        float s2 = p0[1] + p0[3] + p1[1] + p1[3];
        float mean = s1 * (1.f / 256.f);
        float var  = s2 * (1.f / 256.f) - mean * mean;
        float rstd = rsqrtf(var + 1e-5f);
        #pragma unroll
        for (int ni = 0; ni < 4; ++ni) {
            f32x4 gv  = *(const f32x4*)(smem + BCF + c1off + (ni << 6));
            f32x4 bev = *(const f32x4*)(smem + BCF + 1024 + c1off + (ni << 6));
            bf16x4 hb;
            #pragma unroll
            for (int j = 0; j < 4; ++j) {
                float h = (pv[mi][ni][j] - mean) * rstd * gv[j] + bev[j];
                hb[j] = (bf16)fmaxf(h, 0.f);
            }
            uint32_t byte = ((uint32_t)row << 9) + ((uint32_t)wn << 7) + ((uint32_t)ni << 5) + ((uint32_t)l4 << 3);
            byte ^= ((byte >> 9) & 7u) << 4;
            *(bf16x4*)(smem + SOFF + byte) = hb;
        }
    }
    __syncthreads();

    // ---- GEMM2 (swapped): acc init = b2; h1[64x256] @ w2[256x128] ----
    f32x4 acc2s[2][2];
    #pragma unroll
    for (int ni = 0; ni < 2; ++ni) {
        f32x4 bias = *(const f32x4*)(smem + BCF + 2048 + c2off + (ni << 6));
        acc2s[0][ni] = bias; acc2s[1][ni] = bias;
    }
    const bf16* bp2 = w2f + (wn << 10) + (lane << 3);
    #pragma unroll
    for (int c = 0; c < 8; ++c) {
        bf16x8 a2[2];
        #pragma unroll
        for (int mi = 0; mi < 2; ++mi)
            a2[mi] = *(const bf16x8*)(smem + SOFF + ((abase[mi] + ((uint32_t)c << 6) + koff) ^ asw[mi]));
        #pragma unroll
        for (int ni = 0; ni < 2; ++ni) {
            bf16x8 b2r = *(const bf16x8*)(bp2 + (c << 12) + (ni << 9));
            #pragma unroll
            for (int mi = 0; mi < 2; ++mi)
                acc2s[mi][ni] = __builtin_amdgcn_mfma_f32_16x16x32_bf16(
                    b2r, a2[mi], acc2s[mi][ni], 0, 0, 0);
        }
    }

    // ---- LN2 stats ----
    #pragma unroll
    for (int mi = 0; mi < 2; ++mi) {
        float s1 = 0.f, s2 = 0.f;
        #pragma unroll
        for (int ni = 0; ni < 2; ++ni)
            #pragma unroll
            for (int j = 0; j < 4; ++j) {
                float v = acc2s[mi][ni][j];
                s1 += v; s2 += v * v;
            }
        s1 += __shfl_xor(s1, 16); s1 += __shfl_xor(s1, 32);
        s2 += __shfl_xor(s2, 16); s2 += __shfl_xor(s2, 32);
        if (l4 == 0) {
            int row = (wm << 5) + (mi << 4) + l15;
            *(float2*)(smem + BSCR + (row << 5) + (wn << 3)) = make_float2(s1, s2);
        }
    }
    __syncthreads();

    // ---- LN2 apply + ReLU + w3 dot ----
    #pragma unroll
    for (int mi = 0; mi < 2; ++mi) {
        int row = (wm << 5) + (mi << 4) + l15;
        f32x4 p0 = *(const f32x4*)(smem + BSCR + (row << 5));
        f32x4 p1 = *(const f32x4*)(smem + BSCR + (row << 5) + 16);
        float s1 = p0[0] + p0[2] + p1[0] + p1[2];
        float s2 = p0[1] + p0[3] + p1[1] + p1[3];
        float mean = s1 * (1.f / 128.f);
        float var  = s2 * (1.f / 128.f) - mean * mean;
        float rstd = rsqrtf(var + 1e-5f);
        float zp = 0.f;
        #pragma unroll
        for (int ni = 0; ni < 2; ++ni) {
            f32x4 gv  = *(const f32x4*)(smem + BCF + 2560 + c2off + (ni << 6));
            f32x4 bev = *(const f32x4*)(smem + BCF + 3072 + c2off + (ni << 6));
            f32x4 wv  = *(const f32x4*)(smem + BCF + 3584 + c2off + (ni << 6));
            #pragma unroll
            for (int j = 0; j < 4; ++j) {
                float h = (acc2s[mi][ni][j] - mean) * rstd * gv[j] + bev[j];
                h = fmaxf(h, 0.f);
                zp += h * wv[j];
            }
        }
        zp += __shfl_xor(zp, 16); zp += __shfl_xor(zp, 32);
        if (l4 == 0)
            *(float*)(smem + BSCR2 + (row << 4) + (wn << 2)) = zp;
    }
    __syncthreads();

    if (wn == 0) {
        const float b3s = b3[0];
        #pragma unroll
        for (int mi = 0; mi < 2; ++mi) {
            int row = (wm << 5) + (mi << 4) + l15;
            if (l4 == 0) {
                f32x4 zv = *(const f32x4*)(smem + BSCR2 + (row << 4));
                float z = zv[0] + zv[1] + zv[2] + zv[3] + b3s;
                out[gr0 + row] = 1.f / (1.f + expf(-z));
            }
        }
    }
}

// ===================== old path (r12, 270us, known good) =====================
#define AOFF  0
#define SCR   32768
#define SCR2  34816
#define CFOFF 35840
#define SMEM_BYTES 40960

__global__ void preconv(const float* __restrict__ x, const float* __restrict__ w1,
                        const float* __restrict__ w2, bf16* __restrict__ ws,
                        float* __restrict__ out) {
    int gi = blockIdx.x * 256 + threadIdx.x;
    if (gi < ROWS) out[ROWS + gi] = (gi < EPOS) ? 1.f : 0.f;
    int i = gi;
    if (i < XB_N) { ws[i] = (bf16)x[i]; return; }
    i -= XB_N;
    if (i < WAF_N) {
        int j = i & 7, l = (i >> 3) & 63, ct = i >> 9;
        int c = ct >> 4, t = ct & 15;
        int n = t * 16 + (l & 15);
        int k = c * 32 + (l >> 4) * 8 + j;
        ws[WAF_E + i] = (bf16)w1[k * H1C + n];
        return;
    }
    i -= WAF_N;
    if (i < W2F_N) {
        int j = i & 7, l = (i >> 3) & 63, ct = i >> 9;
        int c = ct >> 3, t = ct & 7;
        int n = t * 16 + (l & 15);
        int k = c * 32 + (l >> 4) * 8 + j;
        ws[W2F_E + i] = (bf16)w2[k * H2C + n];
    }
}

__global__ __launch_bounds__(NTH, 4) void lp_mfma11(
    const bf16* __restrict__ xb, const bf16* __restrict__ w1f, const bf16* __restrict__ w2f,
    const int*  __restrict__ ei, const int* __restrict__ nei,
    const float* __restrict__ b1, const float* __restrict__ g1, const float* __restrict__ be1,
    const float* __restrict__ b2, const float* __restrict__ g2, const float* __restrict__ be2,
    const float* __restrict__ w3, const float* __restrict__ b3,
    float* __restrict__ out)
{
    extern __shared__ char smem[];
    const int tid  = threadIdx.x;
    const int lane = tid & 63;
    const int w    = tid >> 6;
    const int wm   = w >> 2;
    const int wn   = w & 3;
    const int gr0  = blockIdx.x * MT;
    const int l15  = lane & 15;
    const int l4   = lane >> 4;

    #pragma unroll
    for (int ii = 0; ii < 4; ++ii) {
        const int i = w * 4 + ii;
        uint32_t doff = (uint32_t)(i << 10) + (uint32_t)(lane << 4);
        uint32_t loff = doff ^ (((doff >> 9) & 7u) << 4);
        int row = loff >> 9;
        int inb = loff & 511;
        int gr  = gr0 + row;
        int node;
        if (inb < 256) { node = (gr < EPOS) ? ei[gr]        : nei[gr - EPOS]; }
        else           { node = (gr < EPOS) ? ei[EPOS + gr] : nei[gr]; inb -= 256; }
        gll16((const char*)xb + (((size_t)node) << 8) + inb, smem + AOFF + (i << 10));
    }
    for (int i = tid; i < 1280; i += NTH) {
        float v;
        if      (i < 256)  v = b1[i];
        else if (i < 512)  v = g1[i - 256];
        else if (i < 768)  v = be1[i - 512];
        else if (i < 896)  v = b2[i - 768];
        else if (i < 1024) v = g2[i - 896];
        else if (i < 1152) v = be2[i - 1024];
        else               v = w3[i - 1152];
        *(float*)(smem + CFOFF + i * 4) = v;
    }
    uint32_t abase[2], asw[2];
    #pragma unroll
    for (int mi = 0; mi < 2; ++mi) {
        int row = (wm << 5) + (mi << 4) + l15;
        abase[mi] = (uint32_t)row << 9;
        asw[mi]   = (uint32_t)(row & 7) << 4;
    }
    const uint32_t koff  = (uint32_t)l4 << 4;
    const uint32_t c1off = ((uint32_t)wn << 8) + ((uint32_t)l4 << 4);
    const uint32_t c2off = ((uint32_t)wn << 7) + ((uint32_t)l4 << 4);
    __syncthreads();

    f32x4 acc1s[2][4];
    #pragma unroll
    for (int ni = 0; ni < 4; ++ni) {
        f32x4 bias = *(const f32x4*)(smem + CFOFF + c1off + (ni << 6));
        acc1s[0][ni] = bias; acc1s[1][ni] = bias;
    }
    const bf16* bp1 = w1f + (wn << 11) + (lane << 3);
    #pragma unroll
    for (int c = 0; c < 8; ++c) {
        bf16x8 af[2];
        #pragma unroll
        for (int mi = 0; mi < 2; ++mi)
            af[mi] = *(const bf16x8*)(smem + AOFF + ((abase[mi] + ((uint32_t)c << 6) + koff) ^ asw[mi]));
        #pragma unroll
        for (int ni = 0; ni < 4; ++ni) {
            bf16x8 bfr = *(const bf16x8*)(bp1 + (c << 13) + (ni << 9));
            #pragma unroll
            for (int mi = 0; mi < 2; ++mi)
                acc1s[mi][ni] = __builtin_amdgcn_mfma_f32_16x16x32_bf16(
                    bfr, af[mi], acc1s[mi][ni], 0, 0, 0);
        }
    }
    #pragma unroll
    for (int mi = 0; mi < 2; ++mi) {
        float s1 = 0.f, s2 = 0.f;
        #pragma unroll
        for (int ni = 0; ni < 4; ++ni)
            #pragma unroll
            for (int j = 0; j < 4; ++j) {
                float v = acc1s[mi][ni][j];
                s1 += v; s2 += v * v;
            }
        s1 += __shfl_xor(s1, 16); s1 += __shfl_xor(s1, 32);
        s2 += __shfl_xor(s2, 16); s2 += __shfl_xor(s2, 32);
        if (l4 == 0) {
            int row = (wm << 5) + (mi << 4) + l15;
            *(float2*)(smem + SCR + (row << 5) + (wn << 3)) = make_float2(s1, s2);
        }
    }
    __syncthreads();
    #pragma unroll
    for (int mi = 0; mi < 2; ++mi) {
        int row = (wm << 5) + (mi << 4) + l15;
        f32x4 p0 = *(const f32x4*)(smem + SCR + (row << 5));
        f32x4 p1 = *(const f32x4*)(smem + SCR + (row << 5) + 16);
        float s1 = p0[0] + p0[2] + p1[0] + p1[2];
        float s2 = p0[1] + p0[3] + p1[1] + p1[3];
        float mean = s1 * (1.f / 256.f);
        float var  = s2 * (1.f / 256.f) - mean * mean;
        float rstd = rsqrtf(var + 1e-5f);
        #pragma unroll
        for (int ni = 0; ni < 4; ++ni) {
            f32x4 gv  = *(const f32x4*)(smem + CFOFF + 1024 + c1off + (ni << 6));
            f32x4 bev = *(const f32x4*)(smem + CFOFF + 2048 + c1off + (ni << 6));
            bf16x4 hb;
            #pragma unroll
            for (int j = 0; j < 4; ++j) {
                float h = (acc1s[mi][ni][j] - mean) * rstd * gv[j] + bev[j];
                hb[j] = (bf16)fmaxf(h, 0.f);
            }
            uint32_t byte = ((uint32_t)row << 9) + ((uint32_t)wn << 7) + ((uint32_t)ni << 5) + ((uint32_t)l4 << 3);
            byte ^= ((byte >> 9) & 7u) << 4;
            *(bf16x4*)(smem + AOFF + byte) = hb;
        }
    }
    __syncthreads();

    f32x4 acc2s[2][2];
    #pragma unroll
    for (int ni = 0; ni < 2; ++ni) {
        f32x4 bias = *(const f32x4*)(smem + CFOFF + 3072 + c2off + (ni << 6));
        acc2s[0][ni] = bias; acc2s[1][ni] = bias;
    }
    const bf16* bp2 = w2f + (wn << 10) + (lane << 3);
    #pragma unroll
    for (int c = 0; c < 8; ++c) {
        bf16x8 a2[2];
        #pragma unroll
        for (int mi = 0; mi < 2; ++mi)
            a2[mi] = *(const bf16x8*)(smem + AOFF + ((abase[mi] + ((uint32_t)c << 6) + koff) ^ asw[mi]));
        #pragma unroll
        for (int ni = 0; ni < 2; ++ni) {
            bf16x8 b2r = *(const bf16x8*)(bp2 + (c << 12) + (ni << 9));
            #pragma unroll
            for (int mi = 0; mi < 2; ++mi)
                acc2s[mi][ni] = __builtin_amdgcn_mfma_f32_16x16x32_bf16(
                    b2r, a2[mi], acc2s[mi][ni], 0, 0, 0);
        }
    }
    #pragma unroll
    for (int mi = 0; mi < 2; ++mi) {
        float s1 = 0.f, s2 = 0.f;
        #pragma unroll
        for (int ni = 0; ni < 2; ++ni)
            #pragma unroll
            for (int j = 0; j < 4; ++j) {
                float v = acc2s[mi][ni][j];
                s1 += v; s2 += v * v;
            }
        s1 += __shfl_xor(s1, 16); s1 += __shfl_xor(s1, 32);
        s2 += __shfl_xor(s2, 16); s2 += __shfl_xor(s2, 32);
        if (l4 == 0) {
            int row = (wm << 5) + (mi << 4) + l15;
            *(float2*)(smem + SCR + (row << 5) + (wn << 3)) = make_float2(s1, s2);
        }
    }
    __syncthreads();
    #pragma unroll
    for (int mi = 0; mi < 2; ++mi) {
        int row = (wm << 5) + (mi << 4) + l15;
        f32x4 p0 = *(const f32x4*)(smem + SCR + (row << 5));
        f32x4 p1 = *(const f32x4*)(smem + SCR + (row << 5) + 16);
        float s1 = p0[0] + p0[2] + p1[0] + p1[2];
        float s2 = p0[1] + p0[3] + p1[1] + p1[3];
        float mean = s1 * (1.f / 128.f);
        float var  = s2 * (1.f / 128.f) - mean * mean;
        float rstd = rsqrtf(var + 1e-5f);
        float zp = 0.f;
        #pragma unroll
        for (int ni = 0; ni < 2; ++ni) {
            f32x4 gv  = *(const f32x4*)(smem + CFOFF + 3584 + c2off + (ni << 6));
            f32x4 bev = *(const f32x4*)(smem + CFOFF + 4096 + c2off + (ni << 6));
            f32x4 wv  = *(const f32x4*)(smem + CFOFF + 4608 + c2off + (ni << 6));
            #pragma unroll
            for (int j = 0; j < 4; ++j) {
                float h = (acc2s[mi][ni][j] - mean) * rstd * gv[j] + bev[j];
                h = fmaxf(h, 0.f);
                zp += h * wv[j];
            }
        }
        zp += __shfl_xor(zp, 16); zp += __shfl_xor(zp, 32);
        if (l4 == 0)
            *(float*)(smem + SCR2 + (row << 4) + (wn << 2)) = zp;
    }
    __syncthreads();
    if (wn == 0) {
        const float b3s = b3[0];
        #pragma unroll
        for (int mi = 0; mi < 2; ++mi) {
            int row = (wm << 5) + (mi << 4) + l15;
            if (l4 == 0) {
                f32x4 zv = *(const f32x4*)(smem + SCR2 + (row << 4));
                float z = zv[0] + zv[1] + zv[2] + zv[3] + b3s;
                out[gr0 + row] = 1.f / (1.f + expf(-z));
            }
        }
    }
}

// ===================== ultimate fallback (round-1 kernel) =====================
#define TILE  32
#define PAD   264
__global__ __launch_bounds__(256, 4) void lp_fused(
    const float* __restrict__ x, const int* __restrict__ ei, const int* __restrict__ nei,
    const float* __restrict__ w1, const float* __restrict__ b1,
    const float* __restrict__ g1, const float* __restrict__ be1,
    const float* __restrict__ w2, const float* __restrict__ b2,
    const float* __restrict__ g2, const float* __restrict__ be2,
    const float* __restrict__ w3, const float* __restrict__ b3,
    float* __restrict__ out)
{
    __shared__ float lds[TILE][PAD];
    const int t = threadIdx.x, e = t >> 3, jg = t & 7;
    const int row = blockIdx.x * TILE + e;
    {
        int src, dst;
        if (row < EPOS) { src = ei[row];         dst = ei[EPOS + row]; }
        else            { src = nei[row - EPOS]; dst = nei[row]; }
        const float* base = (jg < 4) ? (x + src * DIM + jg * 32) : (x + dst * DIM + (jg - 4) * 32);
        const float4* b4 = (const float4*)base;
        #pragma unroll
        for (int s = 0; s < 8; ++s) *(float4*)&lds[e][jg * 32 + s * 4] = b4[s];
    }
    __syncthreads();
    float acc[32];
    #pragma unroll
    for (int i = 0; i < 32; ++i) acc[i] = 0.f;
    const int j0 = jg * 32;
    for (int k4 = 0; k4 < D2 / 4; ++k4) {
        float4 a4 = *(const float4*)&lds[e][k4 * 4];
        float av[4] = {a4.x, a4.y, a4.z, a4.w};
        #pragma unroll
        for (int kk = 0; kk < 4; ++kk) {
            const float a = av[kk];
            const float4* wr = (const float4*)(w1 + (k4 * 4 + kk) * H1C + j0);
            #pragma unroll
            for (int ii = 0; ii < 8; ++ii) {
                float4 wv = wr[ii];
                acc[ii*4+0] += a*wv.x; acc[ii*4+1] += a*wv.y; acc[ii*4+2] += a*wv.z; acc[ii*4+3] += a*wv.w;
            }
        }
    }
    float s1 = 0.f, s2 = 0.f;
    #pragma unroll
    for (int i = 0; i < 32; ++i) { float h = acc[i] + b1[j0+i]; acc[i] = h; s1 += h; s2 += h*h; }
    #pragma unroll
    for (int m = 1; m < 8; m <<= 1) { s1 += __shfl_xor(s1, m, 8); s2 += __shfl_xor(s2, m, 8); }
    float mean = s1 * (1.f/256.f), var = s2 * (1.f/256.f) - mean*mean, rstd = rsqrtf(var + 1e-5f);
    __syncthreads();
    #pragma unroll
    for (int i = 0; i < 32; ++i)
        lds[e][j0+i] = fmaxf((acc[i]-mean)*rstd*g1[j0+i]+be1[j0+i], 0.f);
    __syncthreads();
    float acc2[16];
    #pragma unroll
    for (int i = 0; i < 16; ++i) acc2[i] = 0.f;
    const int q0 = jg * 16;
    for (int k4 = 0; k4 < H1C / 4; ++k4) {
        float4 a4 = *(const float4*)&lds[e][k4 * 4];
        float av[4] = {a4.x, a4.y, a4.z, a4.w};
        #pragma unroll
        for (int kk = 0; kk < 4; ++kk) {
            const float a = av[kk];
            const float4* wr = (const float4*)(w2 + (k4 * 4 + kk) * H2C + q0);
            #pragma unroll
            for (int ii = 0; ii < 4; ++ii) {
                float4 wv = wr[ii];
                acc2[ii*4+0] += a*wv.x; acc2[ii*4+1] += a*wv.y; acc2[ii*4+2] += a*wv.z; acc2[ii*4+3] += a*wv.w;
            }
        }
    }
    s1 = 0.f; s2 = 0.f;
    #pragma unroll
    for (int i = 0; i < 16; ++i) { float h = acc2[i] + b2[q0+i]; acc2[i] = h; s1 += h; s2 += h*h; }
    #pragma unroll
    for (int m = 1; m < 8; m <<= 1) { s1 += __shfl_xor(s1, m, 8); s2 += __shfl_xor(s2, m, 8); }
    mean = s1 * (1.f/128.f); var = s2 * (1.f/128.f) - mean*mean; rstd = rsqrtf(var + 1e-5f);
    float zp = 0.f;
    #pragma unroll
    for (int i = 0; i < 16; ++i) {
        float h = fmaxf((acc2[i]-mean)*rstd*g2[q0+i]+be2[q0+i], 0.f);
        zp += h * w3[q0+i];
    }
    #pragma unroll
    for (int m = 1; m < 8; m <<= 1) zp += __shfl_xor(zp, m, 8);
    if (jg == 0) out[row] = 1.f / (1.f + expf(-(zp + b3[0])));
    if (jg == 1) out[ROWS + row] = (row < EPOS) ? 1.f : 0.f;
}

// ===================== host =====================
extern "C" void kernel_launch(void* const* d_in, const int* in_sizes, int n_in,
                              void* d_out, int out_size, void* d_ws, size_t ws_size,
                              hipStream_t stream) {
    const float* x   = (const float*)d_in[0];
    const int*   ei  = (const int*)d_in[1];
    const int*   nei = (const int*)d_in[3];
    const float* w1  = (const float*)d_in[4];
    const float* b1  = (const float*)d_in[5];
    const float* g1  = (const float*)d_in[6];
    const float* be1 = (const float*)d_in[7];
    const float* w2  = (const float*)d_in[8];
    const float* b2  = (const float*)d_in[9];
    const float* g2  = (const float*)d_in[10];
    const float* be2 = (const float*)d_in[11];
    const float* w3  = (const float*)d_in[12];
    const float* b3  = (const float*)d_in[13];
    float* out = (float*)d_out;

    if (ws_size >= WS2_NEEDED) {
        bf16* ws = (bf16*)d_ws;
        const int total = XB_N + WAF_N + W2F_N;
        hipLaunchKernelGGL(preconv2, dim3((total + 255) / 256), dim3(256), 0, stream,
                           x, w1, w2, ws, out);
        hipLaunchKernelGGL(node_gemm, dim3((NN + 63) / 64), dim3(512), 0, stream,
                           ws, ws + WAF_E, b1, ws + Y_E);
        hipFuncSetAttribute((const void*)lp_edge,
                            hipFuncAttributeMaxDynamicSharedMemorySize, BSMEM);
        hipLaunchKernelGGL(lp_edge, dim3(ROWS / MT), dim3(NTH), BSMEM, stream,
                           ws + Y_E, ws + W2F_E, ei, nei,
                           g1, be1, b2, g2, be2, w3, b3, out);
    } else if (ws_size >= WS1_NEEDED) {
        bf16* ws = (bf16*)d_ws;
        const int total = XB_N + WAF_N + W2F_N;
        hipLaunchKernelGGL(preconv, dim3((total + 255) / 256), dim3(256), 0, stream,
                           x, w1, w2, ws, out);
        hipFuncSetAttribute((const void*)lp_mfma11,
                            hipFuncAttributeMaxDynamicSharedMemorySize, SMEM_BYTES);
        hipLaunchKernelGGL(lp_mfma11, dim3(ROWS / MT), dim3(NTH), SMEM_BYTES, stream,
                           ws, ws + WAF_E, ws + W2F_E, ei, nei,
                           b1, g1, be1, b2, g2, be2, w3, b3, out);
    } else {
        hipLaunchKernelGGL(lp_fused, dim3(ROWS / TILE), dim3(256), 0, stream,
                           x, ei, nei, w1, b1, g1, be1, w2, b2, g2, be2, w3, b3, out);
    }
}

// Round 15
// 247.784 us; speedup vs baseline: 1.1689x; 1.1689x over previous
//
#include <hip/hip_runtime.h>
#include <math.h>
#include <stdint.h>

// Problem constants
#define NN    50000
#define EPOS  400000
#define ROWS  800000
#define DIM   128
#define D2    256
#define H1C   256
#define H2C   128
#define MT    64            // edge rows per block
#define NTH   512           // 8 waves

typedef __bf16 bf16;
typedef __bf16 bf16x8 __attribute__((ext_vector_type(8)));
typedef __bf16 bf16x4 __attribute__((ext_vector_type(4)));
typedef float  f32x4  __attribute__((ext_vector_type(4)));

// ---- workspace element offsets (bf16 elements) ----
#define XB_N   (NN*DIM)             // 6,400,000: x as bf16 [node][128]
#define W1F_E  XB_N
#define W1F_N  (H1C*D2)             // w1 in fragment order (c-major)
#define W2F_E  (W1F_E + W1F_N)
#define W2F_N  (H2C*H1C)
#define OFFS_E (W2F_E + W2F_N)      // u32 offs[2*ROWS]: src byte-off | dst byte-off
#define WS_NEEDED ((size_t)OFFS_E * 2 + (size_t)2 * ROWS * 4)   // ~19.4 MB

// ---- LDS byte offsets (40,960 B total) ----
#define AOFF  0        // 32KB: buf [64 rows][512B]; A (src|dst bf16) then h1; 3-bit XOR swizzle
#define SCR   32768    // 2KB  LN scratch [64 rows][4 wn] x float2
#define SCR2  34816    // 1KB  z scratch  [64 rows][4 wn] x float
#define CFOFF 35840    // 5KB  f32 coeffs: b1[256] g1[256] be1[256] b2[128] g2[128] be2[128] w3[128]
#define SMEM_BYTES 40960

__device__ __forceinline__ void gll16(const void* g, void* l) {
    __builtin_amdgcn_global_load_lds(
        (const __attribute__((address_space(1))) void*)g,
        (__attribute__((address_space(3))) void*)l, 16, 0, 0);
}

// ===================== pre-convert kernel (x, w1f, w2f, offs, labels) ========
// w1f flat = ((c*16 + t)*64 + l)*8 + j ; n = t*16 + (l&15), k = c*32 + (l>>4)*8 + j
// w2f flat = ((c*8  + t)*64 + l)*8 + j ; same (t<8)
__global__ void preconv3(const float* __restrict__ x, const float* __restrict__ w1,
                         const float* __restrict__ w2,
                         const int* __restrict__ ei, const int* __restrict__ nei,
                         bf16* __restrict__ ws, float* __restrict__ out) {
    int gi = blockIdx.x * 256 + threadIdx.x;
    if (gi < ROWS) out[ROWS + gi] = (gi < EPOS) ? 1.f : 0.f;   // labels
    int i = gi;
    if (i < XB_N) { ws[i] = (bf16)x[i]; return; }
    i -= XB_N;
    if (i < W1F_N) {
        int j = i & 7, l = (i >> 3) & 63, ct = i >> 9;   // ct 0..127
        int c = ct >> 4, t = ct & 15;
        int n = t * 16 + (l & 15);
        int k = c * 32 + (l >> 4) * 8 + j;
        ws[W1F_E + i] = (bf16)w1[k * H1C + n];
        return;
    }
    i -= W1F_N;
    if (i < W2F_N) {
        int j = i & 7, l = (i >> 3) & 63, ct = i >> 9;   // ct 0..63
        int c = ct >> 3, t = ct & 7;
        int n = t * 16 + (l & 15);
        int k = c * 32 + (l >> 4) * 8 + j;
        ws[W2F_E + i] = (bf16)w2[k * H2C + n];
        return;
    }
    i -= W2F_N;
    if (i < 2 * ROWS) {
        uint32_t* offs = (uint32_t*)(ws + OFFS_E);
        int node;
        if (i < ROWS) node = (i < EPOS) ? ei[i] : nei[i - EPOS];
        else { int gr = i - ROWS; node = (gr < EPOS) ? ei[EPOS + gr] : nei[gr]; }
        offs[i] = (uint32_t)node << 8;
    }
}

// ====== fused MFMA kernel (r12 + tree reductions + offset table) =============
__global__ __launch_bounds__(NTH, 4) void lp_mfma13(
    const bf16* __restrict__ xb, const bf16* __restrict__ w1f, const bf16* __restrict__ w2f,
    const uint32_t* __restrict__ offs,
    const float* __restrict__ b1, const float* __restrict__ g1, const float* __restrict__ be1,
    const float* __restrict__ b2, const float* __restrict__ g2, const float* __restrict__ be2,
    const float* __restrict__ w3, const float* __restrict__ b3,
    float* __restrict__ out)
{
    extern __shared__ char smem[];
    const int tid  = threadIdx.x;
    const int lane = tid & 63;
    const int w    = tid >> 6;        // wave 0..7
    const int wm   = w >> 2;          // M half (0..1): 32 rows
    const int wn   = w & 3;           // N quarter
    const int gr0  = blockIdx.x * MT;
    const int l15  = lane & 15;
    const int l4   = lane >> 4;       // 0..3

    // ---- stage A once: [64 rows][512B] = src|dst bf16 rows, swizzled ----
    #pragma unroll
    for (int ii = 0; ii < 4; ++ii) {
        const int i = w * 4 + ii;                         // 0..31, 1KB each
        uint32_t doff = (uint32_t)(i << 10) + (uint32_t)(lane << 4);
        uint32_t loff = doff ^ (((doff >> 9) & 7u) << 4); // inverse swizzle (involution)
        int row = loff >> 9;                              // 0..63
        int inb = loff & 511;
        int idx = gr0 + row + ((inb >> 8) ? ROWS : 0);    // src table | dst table
        uint32_t off = offs[idx];
        gll16((const char*)xb + off + (inb & 255), smem + AOFF + (i << 10));
    }

    // ---- stage LN coeffs into LDS (1280 f32) ----
    for (int i = tid; i < 1280; i += NTH) {
        float v;
        if      (i < 256)  v = b1[i];
        else if (i < 512)  v = g1[i - 256];
        else if (i < 768)  v = be1[i - 512];
        else if (i < 896)  v = b2[i - 768];
        else if (i < 1024) v = g2[i - 896];
        else if (i < 1152) v = be2[i - 1024];
        else               v = w3[i - 1152];
        *(float*)(smem + CFOFF + i * 4) = v;
    }

    // A-fragment LDS addressing (row = wm*32 + mi*16 + l15)
    uint32_t abase[2], asw[2];
    #pragma unroll
    for (int mi = 0; mi < 2; ++mi) {
        int row = (wm << 5) + (mi << 4) + l15;
        abase[mi] = (uint32_t)row << 9;
        asw[mi]   = (uint32_t)(row & 7) << 4;
    }
    const uint32_t koff  = (uint32_t)l4 << 4;
    const uint32_t c1off = ((uint32_t)wn << 8) + ((uint32_t)l4 << 4);   // layer1 coeff byte, +ni*64
    const uint32_t c2off = ((uint32_t)wn << 7) + ((uint32_t)l4 << 4);   // layer2 coeff byte, +ni*64

    __syncthreads();

    // ---- GEMM1 (swapped): acc init = bias; row = wm*32+mi*16+l15, cols wn*64+ni*16+l4*4+j ----
    f32x4 acc1s[2][4];
    #pragma unroll
    for (int ni = 0; ni < 4; ++ni) {
        f32x4 bias = *(const f32x4*)(smem + CFOFF + c1off + (ni << 6));
        acc1s[0][ni] = bias; acc1s[1][ni] = bias;
    }
    const bf16* bp1 = w1f + (wn << 11) + (lane << 3);   // t = wn*4+ni
    #pragma unroll
    for (int c = 0; c < 8; ++c) {
        bf16x8 af[2];
        #pragma unroll
        for (int mi = 0; mi < 2; ++mi)
            af[mi] = *(const bf16x8*)(smem + AOFF + ((abase[mi] + ((uint32_t)c << 6) + koff) ^ asw[mi]));
        #pragma unroll
        for (int ni = 0; ni < 4; ++ni) {
            bf16x8 bfr = *(const bf16x8*)(bp1 + (c << 13) + (ni << 9));
            #pragma unroll
            for (int mi = 0; mi < 2; ++mi)
                acc1s[mi][ni] = __builtin_amdgcn_mfma_f32_16x16x32_bf16(
                    bfr, af[mi], acc1s[mi][ni], 0, 0, 0);
        }
    }

    // ---- LN1 stats: tree s1, 4 parallel fma-chains for s2 ----
    #pragma unroll
    for (int mi = 0; mi < 2; ++mi) {
        f32x4 t01 = acc1s[mi][0] + acc1s[mi][1];
        f32x4 t23 = acc1s[mi][2] + acc1s[mi][3];
        f32x4 ts  = t01 + t23;
        float s1 = (ts[0] + ts[1]) + (ts[2] + ts[3]);
        float q[4];
        #pragma unroll
        for (int ni = 0; ni < 4; ++ni) {
            f32x4 a = acc1s[mi][ni];
            float m = a[3] * a[3];
            m = fmaf(a[2], a[2], m);
            m = fmaf(a[1], a[1], m);
            m = fmaf(a[0], a[0], m);
            q[ni] = m;
        }
        float s2 = (q[0] + q[1]) + (q[2] + q[3]);
        s1 += __shfl_xor(s1, 16); s1 += __shfl_xor(s1, 32);
        s2 += __shfl_xor(s2, 16); s2 += __shfl_xor(s2, 32);
        if (l4 == 0) {
            int row = (wm << 5) + (mi << 4) + l15;
            *(float2*)(smem + SCR + (row << 5) + (wn << 3)) = make_float2(s1, s2);
        }
    }
    __syncthreads();   // stats ready; all A-reads done -> safe to overwrite buf

    // ---- LN1 apply + ReLU -> h1 (g/be from LDS; packed b64 stores) ----
    #pragma unroll
    for (int mi = 0; mi < 2; ++mi) {
        int row = (wm << 5) + (mi << 4) + l15;
        f32x4 p0 = *(const f32x4*)(smem + SCR + (row << 5));
        f32x4 p1 = *(const f32x4*)(smem + SCR + (row << 5) + 16);
        float s1 = (p0[0] + p0[2]) + (p1[0] + p1[2]);
        float s2 = (p0[1] + p0[3]) + (p1[1] + p1[3]);
        float mean = s1 * (1.f / 256.f);
        float var  = s2 * (1.f / 256.f) - mean * mean;
        float rstd = rsqrtf(var + 1e-5f);
        #pragma unroll
        for (int ni = 0; ni < 4; ++ni) {
            f32x4 gv  = *(const f32x4*)(smem + CFOFF + 1024 + c1off + (ni << 6));
            f32x4 bev = *(const f32x4*)(smem + CFOFF + 2048 + c1off + (ni << 6));
            bf16x4 hb;
            #pragma unroll
            for (int j = 0; j < 4; ++j) {
                float h = (acc1s[mi][ni][j] - mean) * rstd * gv[j] + bev[j];
                hb[j] = (bf16)fmaxf(h, 0.f);
            }
            uint32_t byte = ((uint32_t)row << 9) + ((uint32_t)wn << 7) + ((uint32_t)ni << 5) + ((uint32_t)l4 << 3);
            byte ^= ((byte >> 9) & 7u) << 4;
            *(bf16x4*)(smem + AOFF + byte) = hb;
        }
    }
    __syncthreads();

    // ---- GEMM2 (swapped): acc init = bias; h1[64x256] @ w2[256x128] ----
    f32x4 acc2s[2][2];
    #pragma unroll
    for (int ni = 0; ni < 2; ++ni) {
        f32x4 bias = *(const f32x4*)(smem + CFOFF + 3072 + c2off + (ni << 6));
        acc2s[0][ni] = bias; acc2s[1][ni] = bias;
    }
    const bf16* bp2 = w2f + (wn << 10) + (lane << 3);   // t = wn*2+ni
    #pragma unroll
    for (int c = 0; c < 8; ++c) {
        bf16x8 a2[2];
        #pragma unroll
        for (int mi = 0; mi < 2; ++mi)
            a2[mi] = *(const bf16x8*)(smem + AOFF + ((abase[mi] + ((uint32_t)c << 6) + koff) ^ asw[mi]));
        #pragma unroll
        for (int ni = 0; ni < 2; ++ni) {
            bf16x8 b2r = *(const bf16x8*)(bp2 + (c << 12) + (ni << 9));
            #pragma unroll
            for (int mi = 0; mi < 2; ++mi)
                acc2s[mi][ni] = __builtin_amdgcn_mfma_f32_16x16x32_bf16(
                    b2r, a2[mi], acc2s[mi][ni], 0, 0, 0);
        }
    }

    // ---- LN2 stats: tree s1, 2 parallel fma-chains for s2 ----
    #pragma unroll
    for (int mi = 0; mi < 2; ++mi) {
        f32x4 ts = acc2s[mi][0] + acc2s[mi][1];
        float s1 = (ts[0] + ts[1]) + (ts[2] + ts[3]);
        float q[2];
        #pragma unroll
        for (int ni = 0; ni < 2; ++ni) {
            f32x4 a = acc2s[mi][ni];
            float m = a[3] * a[3];
            m = fmaf(a[2], a[2], m);
            m = fmaf(a[1], a[1], m);
            m = fmaf(a[0], a[0], m);
            q[ni] = m;
        }
        float s2 = q[0] + q[1];
        s1 += __shfl_xor(s1, 16); s1 += __shfl_xor(s1, 32);
        s2 += __shfl_xor(s2, 16); s2 += __shfl_xor(s2, 32);
        if (l4 == 0) {
            int row = (wm << 5) + (mi << 4) + l15;
            *(float2*)(smem + SCR + (row << 5) + (wn << 3)) = make_float2(s1, s2);
        }
    }
    __syncthreads();

    // ---- LN2 apply + ReLU + w3 dot (2 parallel fma-chains) ----
    #pragma unroll
    for (int mi = 0; mi < 2; ++mi) {
        int row = (wm << 5) + (mi << 4) + l15;
        f32x4 p0 = *(const f32x4*)(smem + SCR + (row << 5));
        f32x4 p1 = *(const f32x4*)(smem + SCR + (row << 5) + 16);
        float s1 = (p0[0] + p0[2]) + (p1[0] + p1[2]);
        float s2 = (p0[1] + p0[3]) + (p1[1] + p1[3]);
        float mean = s1 * (1.f / 128.f);
        float var  = s2 * (1.f / 128.f) - mean * mean;
        float rstd = rsqrtf(var + 1e-5f);
        float r[2];
        #pragma unroll
        for (int ni = 0; ni < 2; ++ni) {
            f32x4 gv  = *(const f32x4*)(smem + CFOFF + 3584 + c2off + (ni << 6));
            f32x4 bev = *(const f32x4*)(smem + CFOFF + 4096 + c2off + (ni << 6));
            f32x4 wv  = *(const f32x4*)(smem + CFOFF + 4608 + c2off + (ni << 6));
            float h0 = fmaxf((acc2s[mi][ni][0] - mean) * rstd * gv[0] + bev[0], 0.f);
            float h1 = fmaxf((acc2s[mi][ni][1] - mean) * rstd * gv[1] + bev[1], 0.f);
            float h2 = fmaxf((acc2s[mi][ni][2] - mean) * rstd * gv[2] + bev[2], 0.f);
            float h3 = fmaxf((acc2s[mi][ni][3] - mean) * rstd * gv[3] + bev[3], 0.f);
            float m = h3 * wv[3];
            m = fmaf(h2, wv[2], m);
            m = fmaf(h1, wv[1], m);
            m = fmaf(h0, wv[0], m);
            r[ni] = m;
        }
        float zp = r[0] + r[1];
        zp += __shfl_xor(zp, 16); zp += __shfl_xor(zp, 32);
        if (l4 == 0)
            *(float*)(smem + SCR2 + (row << 4) + (wn << 2)) = zp;
    }
    __syncthreads();

    // ---- final: sigmoid (wn==0 waves; labels handled by preconv) ----
    if (wn == 0) {
        const float b3s = b3[0];
        #pragma unroll
        for (int mi = 0; mi < 2; ++mi) {
            int row = (wm << 5) + (mi << 4) + l15;
            if (l4 == 0) {
                f32x4 zv = *(const f32x4*)(smem + SCR2 + (row << 4));
                float z = (zv[0] + zv[1]) + (zv[2] + zv[3]) + b3s;
                out[gr0 + row] = 1.f / (1.f + expf(-z));
            }
        }
    }
}

// ===================== fallback (round-1 kernel, known correct) =====================
#define TILE  32
#define PAD   264
__global__ __launch_bounds__(256, 4) void lp_fused(
    const float* __restrict__ x, const int* __restrict__ ei, const int* __restrict__ nei,
    const float* __restrict__ w1, const float* __restrict__ b1,
    const float* __restrict__ g1, const float* __restrict__ be1,
    const float* __restrict__ w2, const float* __restrict__ b2,
    const float* __restrict__ g2, const float* __restrict__ be2,
    const float* __restrict__ w3, const float* __restrict__ b3,
    float* __restrict__ out)
{
    __shared__ float lds[TILE][PAD];
    const int t = threadIdx.x, e = t >> 3, jg = t & 7;
    const int row = blockIdx.x * TILE + e;
    {
        int src, dst;
        if (row < EPOS) { src = ei[row];         dst = ei[EPOS + row]; }
        else            { src = nei[row - EPOS]; dst = nei[row]; }
        const float* base = (jg < 4) ? (x + src * DIM + jg * 32) : (x + dst * DIM + (jg - 4) * 32);
        const float4* b4 = (const float4*)base;
        #pragma unroll
        for (int s = 0; s < 8; ++s) *(float4*)&lds[e][jg * 32 + s * 4] = b4[s];
    }
    __syncthreads();
    float acc[32];
    #pragma unroll
    for (int i = 0; i < 32; ++i) acc[i] = 0.f;
    const int j0 = jg * 32;
    for (int k4 = 0; k4 < D2 / 4; ++k4) {
        float4 a4 = *(const float4*)&lds[e][k4 * 4];
        float av[4] = {a4.x, a4.y, a4.z, a4.w};
        #pragma unroll
        for (int kk = 0; kk < 4; ++kk) {
            const float a = av[kk];
            const float4* wr = (const float4*)(w1 + (k4 * 4 + kk) * H1C + j0);
            #pragma unroll
            for (int ii = 0; ii < 8; ++ii) {
                float4 wv = wr[ii];
                acc[ii*4+0] += a*wv.x; acc[ii*4+1] += a*wv.y; acc[ii*4+2] += a*wv.z; acc[ii*4+3] += a*wv.w;
            }
        }
    }
    float s1 = 0.f, s2 = 0.f;
    #pragma unroll
    for (int i = 0; i < 32; ++i) { float h = acc[i] + b1[j0+i]; acc[i] = h; s1 += h; s2 += h*h; }
    #pragma unroll
    for (int m = 1; m < 8; m <<= 1) { s1 += __shfl_xor(s1, m, 8); s2 += __shfl_xor(s2, m, 8); }
    float mean = s1 * (1.f/256.f), var = s2 * (1.f/256.f) - mean*mean, rstd = rsqrtf(var + 1e-5f);
    __syncthreads();
    #pragma unroll
    for (int i = 0; i < 32; ++i)
        lds[e][j0+i] = fmaxf((acc[i]-mean)*rstd*g1[j0+i]+be1[j0+i], 0.f);
    __syncthreads();
    float acc2[16];
    #pragma unroll
    for (int i = 0; i < 16; ++i) acc2[i] = 0.f;
    const int q0 = jg * 16;
    for (int k4 = 0; k4 < H1C / 4; ++k4) {
        float4 a4 = *(const float4*)&lds[e][k4 * 4];
        float av[4] = {a4.x, a4.y, a4.z, a4.w};
        #pragma unroll
        for (int kk = 0; kk < 4; ++kk) {
            const float a = av[kk];
            const float4* wr = (const float4*)(w2 + (k4 * 4 + kk) * H2C + q0);
            #pragma unroll
            for (int ii = 0; ii < 4; ++ii) {
                float4 wv = wr[ii];
                acc2[ii*4+0] += a*wv.x; acc2[ii*4+1] += a*wv.y; acc2[ii*4+2] += a*wv.z; acc2[ii*4+3] += a*wv.w;
            }
        }
    }
    s1 = 0.f; s2 = 0.f;
    #pragma unroll
    for (int i = 0; i < 16; ++i) { float h = acc2[i] + b2[q0+i]; acc2[i] = h; s1 += h; s2 += h*h; }
    #pragma unroll
    for (int m = 1; m < 8; m <<= 1) { s1 += __shfl_xor(s1, m, 8); s2 += __shfl_xor(s2, m, 8); }
    mean = s1 * (1.f/128.f); var = s2 * (1.f/128.f) - mean*mean; rstd = rsqrtf(var + 1e-5f);
    float zp = 0.f;
    #pragma unroll
    for (int i = 0; i < 16; ++i) {
        float h = fmaxf((acc2[i]-mean)*rstd*g2[q0+i]+be2[q0+i], 0.f);
        zp += h * w3[q0+i];
    }
    #pragma unroll
    for (int m = 1; m < 8; m <<= 1) zp += __shfl_xor(zp, m, 8);
    if (jg == 0) out[row] = 1.f / (1.f + expf(-(zp + b3[0])));
    if (jg == 1) out[ROWS + row] = (row < EPOS) ? 1.f : 0.f;
}

// ===================== host =====================
extern "C" void kernel_launch(void* const* d_in, const int* in_sizes, int n_in,
                              void* d_out, int out_size, void* d_ws, size_t ws_size,
                              hipStream_t stream) {
    const float* x   = (const float*)d_in[0];
    const int*   ei  = (const int*)d_in[1];
    const int*   nei = (const int*)d_in[3];
    const float* w1  = (const float*)d_in[4];
    const float* b1  = (const float*)d_in[5];
    const float* g1  = (const float*)d_in[6];
    const float* be1 = (const float*)d_in[7];
    const float* w2  = (const float*)d_in[8];
    const float* b2  = (const float*)d_in[9];
    const float* g2  = (const float*)d_in[10];
    const float* be2 = (const float*)d_in[11];
    const float* w3  = (const float*)d_in[12];
    const float* b3  = (const float*)d_in[13];
    float* out = (float*)d_out;

    if (ws_size >= WS_NEEDED) {
        bf16* ws = (bf16*)d_ws;
        const int total = XB_N + W1F_N + W2F_N + 2 * ROWS;
        hipLaunchKernelGGL(preconv3, dim3((total + 255) / 256), dim3(256), 0, stream,
                           x, w1, w2, ei, nei, ws, out);
        hipFuncSetAttribute((const void*)lp_mfma13,
                            hipFuncAttributeMaxDynamicSharedMemorySize, SMEM_BYTES);
        hipLaunchKernelGGL(lp_mfma13, dim3(ROWS / MT), dim3(NTH), SMEM_BYTES, stream,
                           ws, ws + W1F_E, ws + W2F_E,
                           (const uint32_t*)(ws + OFFS_E),
                           b1, g1, be1, b2, g2, be2, w3, b3, out);
    } else {
        hipLaunchKernelGGL(lp_fused, dim3(ROWS / TILE), dim3(256), 0, stream,
                           x, ei, nei, w1, b1, g1, be1, w2, b2, g2, be2, w3, b3, out);
    }
}